// Round 1
// baseline (1284.854 us; speedup 1.0000x reference)
//
#include <hip/hip_runtime.h>
#include <math.h>

// Problem constants: B=4, C=64, H=W=64, N=H*W=4096.
// All inputs fp32, output fp32 [4,64,64,64] = 1,048,576 elems.
//
// Workspace layout (floats): needs (5<<20)+256 floats = ~21 MB
//   ws + 0<<20 : c1raw  (conv1 pre-BN)          [B,C,N]
//   ws + 1<<20 : theta  (reused later as c2raw) [B,C,N]
//   ws + 2<<20 : phi                            [B,C,N]
//   ws + 3<<20 : g                              [B,C,N]
//   ws + 4<<20 : y      (attention out)         [B,C,N]
//   ws + 5<<20 : stats  (sc1,sh1,sc2,sh2)       [256]
// z lives in d_out (overwritten at the end by bn_relu).

// ---------------------------------------------------------------------------
// 3x3 conv, pad 1. Tile: 32h x 64w per (b,co). 256 thr, 2x4 outputs/thread.
// Optionally applies y = relu(x*sc[c]+sh[c]) to the INPUT while staging
// (fuses conv1's BN+ReLU into the theta/phi/g conv). Zero-pad ring is kept
// zero (pad is in post-BN space).
// NOUT=3 computes three convs sharing every LDS patch read.
// ---------------------------------------------------------------------------
template <int NOUT, bool BNIN, bool BIAS>
__global__ __launch_bounds__(256) void conv3x3_k(
    const float* __restrict__ in,
    const float* __restrict__ w0c, const float* __restrict__ w1c,
    const float* __restrict__ w2c,
    const float* __restrict__ b0c, const float* __restrict__ b1c,
    const float* __restrict__ b2c,
    const float* __restrict__ bnsc, const float* __restrict__ bnsh,
    float* __restrict__ o0, float* __restrict__ o1, float* __restrict__ o2)
{
    __shared__ float patch[34 * 68];  // rows h0-1..h0+32, cols w -1..64 (pw 0..65)
    const int bco = blockIdx.y;
    const int b   = bco >> 6;
    const int co  = bco & 63;
    const int h0  = blockIdx.x << 5;
    const int t   = threadIdx.x;
    const int th  = t >> 4;            // 0..15 -> output rows 2th, 2th+1
    const int tw4 = (t & 15) << 2;     // output cols tw4..tw4+3

    const float* wp[3] = {w0c, w1c, w2c};

    float acc[NOUT][2][4];
#pragma unroll
    for (int o = 0; o < NOUT; ++o)
#pragma unroll
        for (int r = 0; r < 2; ++r)
#pragma unroll
            for (int k = 0; k < 4; ++k) acc[o][r][k] = 0.f;

    for (int ci = 0; ci < 64; ++ci) {
        __syncthreads();  // previous iteration's reads done
        {
            const float* inb = in + (((size_t)(b * 64 + ci)) << 12);
            float sc = 0.f, sh = 0.f;
            if (BNIN) { sc = bnsc[ci]; sh = bnsh[ci]; }
            for (int p = t; p < 34 * 66; p += 256) {
                int ph = p / 66;
                int pw = p - ph * 66;
                int gh = h0 + ph - 1;
                int gw = pw - 1;
                float v = 0.f;
                if (((unsigned)gh < 64u) & ((unsigned)gw < 64u)) {
                    v = inb[(gh << 6) + gw];
                    if (BNIN) v = fmaxf(v * sc + sh, 0.f);
                }
                patch[ph * 68 + pw] = v;
            }
        }
        __syncthreads();

        // per-ci weights (block-uniform -> scalar loads)
        float wreg[NOUT][9];
#pragma unroll
        for (int o = 0; o < NOUT; ++o) {
            const float* wb = wp[o] + ((co << 6) + ci) * 9;
#pragma unroll
            for (int k = 0; k < 9; ++k) wreg[o][k] = wb[k];
        }

        // register-cache 4 patch rows (covers both output rows x 3 kh taps)
        float4 Ar[4], Br[4];
#pragma unroll
        for (int j = 0; j < 4; ++j) {
            Ar[j] = *(const float4*)&patch[(2 * th + j) * 68 + tw4];
            Br[j] = *(const float4*)&patch[(2 * th + j) * 68 + tw4 + 4];
        }
#pragma unroll
        for (int o = 0; o < NOUT; ++o)
#pragma unroll
            for (int r = 0; r < 2; ++r)
#pragma unroll
                for (int kh = 0; kh < 3; ++kh) {
                    const float4 A  = Ar[r + kh];
                    const float4 Bv = Br[r + kh];
                    const float w0 = wreg[o][kh * 3 + 0];
                    const float w1 = wreg[o][kh * 3 + 1];
                    const float w2 = wreg[o][kh * 3 + 2];
                    acc[o][r][0] = fmaf(w0, A.x, fmaf(w1, A.y, fmaf(w2, A.z, acc[o][r][0])));
                    acc[o][r][1] = fmaf(w0, A.y, fmaf(w1, A.z, fmaf(w2, A.w, acc[o][r][1])));
                    acc[o][r][2] = fmaf(w0, A.z, fmaf(w1, A.w, fmaf(w2, Bv.x, acc[o][r][2])));
                    acc[o][r][3] = fmaf(w0, A.w, fmaf(w1, Bv.x, fmaf(w2, Bv.y, acc[o][r][3])));
                }
    }

    float* op[3] = {o0, o1, o2};
    const float* bp[3] = {b0c, b1c, b2c};
#pragma unroll
    for (int o = 0; o < NOUT; ++o) {
        const float bias = BIAS ? bp[o][co] : 0.f;
#pragma unroll
        for (int r = 0; r < 2; ++r) {
            float4 v = make_float4(acc[o][r][0] + bias, acc[o][r][1] + bias,
                                   acc[o][r][2] + bias, acc[o][r][3] + bias);
            *(float4*)&op[o][(((size_t)(b * 64 + co)) << 12) +
                             ((h0 + 2 * th + r) << 6) + tw4] = v;
        }
    }
}

// ---------------------------------------------------------------------------
// BN stats (training-mode, biased var): per channel over B*H*W = 16384 elems.
// Emits scale = gamma*rsqrt(var+eps), shift = beta - mean*scale.
// ---------------------------------------------------------------------------
__global__ __launch_bounds__(256) void bn_stats_k(
    const float* __restrict__ in, const float* __restrict__ gamma,
    const float* __restrict__ beta, float* __restrict__ scale,
    float* __restrict__ shift)
{
    const int c = blockIdx.x;
    const int t = threadIdx.x;
    float s = 0.f, ss = 0.f;
    for (int p = t; p < 4096; p += 256) {  // 4096 float4 = 16384 elems
        int bidx = p >> 10;
        int n4 = (p & 1023) << 2;
        float4 v = *(const float4*)&in[(((size_t)(bidx * 64 + c)) << 12) + n4];
        s += v.x + v.y + v.z + v.w;
        ss += v.x * v.x + v.y * v.y + v.z * v.z + v.w * v.w;
    }
#pragma unroll
    for (int off = 32; off > 0; off >>= 1) {
        s += __shfl_down(s, off);
        ss += __shfl_down(ss, off);
    }
    __shared__ float red[8];
    const int wid = t >> 6;
    if ((t & 63) == 0) { red[wid] = s; red[wid + 4] = ss; }
    __syncthreads();
    if (t == 0) {
        float S = red[0] + red[1] + red[2] + red[3];
        float SS = red[4] + red[5] + red[6] + red[7];
        float mean = S * (1.f / 16384.f);
        float var = SS * (1.f / 16384.f) - mean * mean;
        float sc = gamma[c] * rsqrtf(var + 1e-5f);
        scale[c] = sc;
        shift[c] = beta[c] - mean * sc;
    }
}

// ---------------------------------------------------------------------------
// Flash attention: S = theta^T*phi (per batch), softmax rows, O = P*g^T.
// Q-tile 64 rows, KV-tile 64. 256 thr, 4x4 outer product per thread.
// theta/phi/g are [C][N] per batch; y written as [C][N] (already-transposed).
// ---------------------------------------------------------------------------
__global__ __launch_bounds__(256) void attn_k(
    const float* __restrict__ th_, const float* __restrict__ ph_,
    const float* __restrict__ gg_, float* __restrict__ yy_)
{
    __shared__ float Qs[64 * 68];   // [c][n]
    __shared__ float KVs[64 * 68];  // K phase: [c][m]; V phase: [m][c]
    __shared__ float Ps[64 * 68];   // [m][n]

    const int b   = blockIdx.x >> 6;
    const int q0  = (blockIdx.x & 63) << 6;
    const int t   = threadIdx.x;
    const int qi4 = (t >> 4) << 2;  // rows qi4..qi4+3  (16 lanes/row-group)
    const int kj4 = (t & 15) << 2;  // cols kj4..kj4+3

    const float* thb = th_ + (((size_t)b) << 18);  // C*N = 262144
    const float* phb = ph_ + (((size_t)b) << 18);
    const float* ggb = gg_ + (((size_t)b) << 18);

    // stage Q tile [c][n]
    for (int p = t; p < 1024; p += 256) {
        int cc = p >> 4, n4 = (p & 15) << 2;
        *(float4*)&Qs[cc * 68 + n4] = *(const float4*)&thb[(cc << 12) + q0 + n4];
    }

    float mrow[4], lrow[4], accO[4][4];
#pragma unroll
    for (int a = 0; a < 4; ++a) {
        mrow[a] = -1e30f;
        lrow[a] = 0.f;
#pragma unroll
        for (int bb = 0; bb < 4; ++bb) accO[a][bb] = 0.f;
    }

    for (int m0 = 0; m0 < 4096; m0 += 64) {
        __syncthreads();  // (a) prev PV reads of KVs/Ps done; also publishes Qs
        for (int p = t; p < 1024; p += 256) {  // K tile [c][m]
            int cc = p >> 4, m4 = (p & 15) << 2;
            *(float4*)&KVs[cc * 68 + m4] = *(const float4*)&phb[(cc << 12) + m0 + m4];
        }
        __syncthreads();  // (b) K ready

        float s[4][4];
#pragma unroll
        for (int a = 0; a < 4; ++a)
#pragma unroll
            for (int bb = 0; bb < 4; ++bb) s[a][bb] = 0.f;

#pragma unroll 4
        for (int cc = 0; cc < 64; ++cc) {
            float4 q = *(const float4*)&Qs[cc * 68 + qi4];
            float4 k = *(const float4*)&KVs[cc * 68 + kj4];
            float qa[4] = {q.x, q.y, q.z, q.w};
            float ka[4] = {k.x, k.y, k.z, k.w};
#pragma unroll
            for (int a = 0; a < 4; ++a)
#pragma unroll
                for (int bb = 0; bb < 4; ++bb)
                    s[a][bb] = fmaf(qa[a], ka[bb], s[a][bb]);
        }

        // online softmax (rows spread over 16 lanes: shuffle-xor 1,2,4,8)
        float rmax[4];
#pragma unroll
        for (int a = 0; a < 4; ++a)
            rmax[a] = fmaxf(fmaxf(s[a][0], s[a][1]), fmaxf(s[a][2], s[a][3]));
#pragma unroll
        for (int off = 1; off < 16; off <<= 1)
#pragma unroll
            for (int a = 0; a < 4; ++a)
                rmax[a] = fmaxf(rmax[a], __shfl_xor(rmax[a], off));

        float alpha[4], rsum[4];
#pragma unroll
        for (int a = 0; a < 4; ++a) {
            float mnew = fmaxf(mrow[a], rmax[a]);
            alpha[a] = __expf(mrow[a] - mnew);
            mrow[a] = mnew;
            rsum[a] = 0.f;
#pragma unroll
            for (int bb = 0; bb < 4; ++bb) {
                s[a][bb] = __expf(s[a][bb] - mnew);
                rsum[a] += s[a][bb];
            }
        }
#pragma unroll
        for (int off = 1; off < 16; off <<= 1)
#pragma unroll
            for (int a = 0; a < 4; ++a) rsum[a] += __shfl_xor(rsum[a], off);
#pragma unroll
        for (int a = 0; a < 4; ++a) {
            lrow[a] = lrow[a] * alpha[a] + rsum[a];
#pragma unroll
            for (int bb = 0; bb < 4; ++bb) accO[a][bb] *= alpha[a];
        }

        __syncthreads();  // (c) everyone done reading K from KVs
        // write P^T into Ps[m][n]
#pragma unroll
        for (int bb = 0; bb < 4; ++bb) {
            float4 pv = make_float4(s[0][bb], s[1][bb], s[2][bb], s[3][bb]);
            *(float4*)&Ps[(kj4 + bb) * 68 + qi4] = pv;
        }
        // load V transposed into KVs[m][c]
        for (int p = t; p < 1024; p += 256) {
            int cc = p >> 4, m4 = (p & 15) << 2;
            float4 v = *(const float4*)&ggb[(cc << 12) + m0 + m4];
            KVs[(m4 + 0) * 68 + cc] = v.x;
            KVs[(m4 + 1) * 68 + cc] = v.y;
            KVs[(m4 + 2) * 68 + cc] = v.z;
            KVs[(m4 + 3) * 68 + cc] = v.w;
        }
        __syncthreads();  // (d) Ps and V ready

#pragma unroll 4
        for (int mm = 0; mm < 64; ++mm) {
            float4 p4 = *(const float4*)&Ps[mm * 68 + qi4];
            float4 v4 = *(const float4*)&KVs[mm * 68 + kj4];
            float pa[4] = {p4.x, p4.y, p4.z, p4.w};
            float va[4] = {v4.x, v4.y, v4.z, v4.w};
#pragma unroll
            for (int a = 0; a < 4; ++a)
#pragma unroll
                for (int bb = 0; bb < 4; ++bb)
                    accO[a][bb] = fmaf(pa[a], va[bb], accO[a][bb]);
        }
    }

    float inv[4];
#pragma unroll
    for (int a = 0; a < 4; ++a) inv[a] = 1.f / lrow[a];
#pragma unroll
    for (int bb = 0; bb < 4; ++bb) {
        int ccol = kj4 + bb;
        float4 o4 = make_float4(accO[0][bb] * inv[0], accO[1][bb] * inv[1],
                                accO[2][bb] * inv[2], accO[3][bb] * inv[3]);
        *(float4*)&yy_[(((size_t)b) << 18) + (ccol << 12) + q0 + qi4] = o4;
    }
}

// ---------------------------------------------------------------------------
// z = W(1x1) * y + Wb + x  (residual). 64co x 64n tile per block, 4x4/thread.
// ---------------------------------------------------------------------------
__global__ __launch_bounds__(256) void conv1x1_res_k(
    const float* __restrict__ y, const float* __restrict__ Wmat,
    const float* __restrict__ Wb, const float* __restrict__ x,
    float* __restrict__ z)
{
    __shared__ float Wt[64 * 68];  // [ci][co]
    __shared__ float Ys[64 * 68];  // [ci][n]
    const int b  = blockIdx.x >> 6;
    const int n0 = (blockIdx.x & 63) << 6;
    const int t  = threadIdx.x;
    const int i4 = (t >> 4) << 2;  // co base
    const int j4 = (t & 15) << 2;  // n base

    for (int p = t; p < 4096; p += 256) {
        int co = p >> 6, ci = p & 63;
        Wt[ci * 68 + co] = Wmat[p];
    }
    for (int p = t; p < 1024; p += 256) {
        int ci = p >> 4, n4 = (p & 15) << 2;
        *(float4*)&Ys[ci * 68 + n4] =
            *(const float4*)&y[(((size_t)(b * 64 + ci)) << 12) + n0 + n4];
    }
    __syncthreads();

    float acc[4][4];
#pragma unroll
    for (int a = 0; a < 4; ++a)
#pragma unroll
        for (int bb = 0; bb < 4; ++bb) acc[a][bb] = 0.f;

#pragma unroll 4
    for (int ci = 0; ci < 64; ++ci) {
        float4 w = *(const float4*)&Wt[ci * 68 + i4];
        float4 yv = *(const float4*)&Ys[ci * 68 + j4];
        float wa[4] = {w.x, w.y, w.z, w.w};
        float ya[4] = {yv.x, yv.y, yv.z, yv.w};
#pragma unroll
        for (int a = 0; a < 4; ++a)
#pragma unroll
            for (int bb = 0; bb < 4; ++bb)
                acc[a][bb] = fmaf(wa[a], ya[bb], acc[a][bb]);
    }
#pragma unroll
    for (int a = 0; a < 4; ++a) {
        int co = i4 + a;
        size_t base = (((size_t)(b * 64 + co)) << 12) + n0 + j4;
        float4 xv = *(const float4*)&x[base];
        float bias = Wb[co];
        float4 r = make_float4(acc[a][0] + bias + xv.x, acc[a][1] + bias + xv.y,
                               acc[a][2] + bias + xv.z, acc[a][3] + bias + xv.w);
        *(float4*)&z[base] = r;
    }
}

// ---------------------------------------------------------------------------
// out = relu(in*scale[c] + shift[c]), vectorized float4.
// ---------------------------------------------------------------------------
__global__ __launch_bounds__(256) void bn_relu_k(
    const float* __restrict__ in, const float* __restrict__ scale,
    const float* __restrict__ shift, float* __restrict__ out)
{
    int p = blockIdx.x * 256 + threadIdx.x;  // p < 262144 float4s
    int c = (p >> 10) & 63;
    float sc = scale[c], sh = shift[c];
    float4 v = *(const float4*)&in[(size_t)p << 2];
    float4 r = make_float4(fmaxf(v.x * sc + sh, 0.f), fmaxf(v.y * sc + sh, 0.f),
                           fmaxf(v.z * sc + sh, 0.f), fmaxf(v.w * sc + sh, 0.f));
    *(float4*)&out[(size_t)p << 2] = r;
}

// ---------------------------------------------------------------------------
extern "C" void kernel_launch(void* const* d_in, const int* in_sizes, int n_in,
                              void* d_out, int out_size, void* d_ws,
                              size_t ws_size, hipStream_t stream)
{
    const float* x    = (const float*)d_in[0];
    const float* c1w  = (const float*)d_in[1];
    const float* bn1g = (const float*)d_in[2];
    const float* bn1b = (const float*)d_in[3];
    const float* thw  = (const float*)d_in[4];
    const float* thb  = (const float*)d_in[5];
    const float* phw  = (const float*)d_in[6];
    const float* phb  = (const float*)d_in[7];
    const float* gw   = (const float*)d_in[8];
    const float* gb   = (const float*)d_in[9];
    const float* Wwt  = (const float*)d_in[10];
    const float* Wbs  = (const float*)d_in[11];
    const float* c2w  = (const float*)d_in[12];
    const float* bn2g = (const float*)d_in[13];
    const float* bn2b = (const float*)d_in[14];
    float* out = (float*)d_out;

    float* ws    = (float*)d_ws;
    float* c1raw = ws;                 // 1M floats
    float* th_   = ws + (1 << 20);     // theta; reused as c2raw
    float* ph_   = ws + (2 << 20);
    float* g_    = ws + (3 << 20);
    float* y_    = ws + (4 << 20);
    float* stats = ws + (5 << 20);     // 256 floats
    float* sc1 = stats, *sh1 = stats + 64, *sc2 = stats + 128, *sh2 = stats + 192;
    float* z_    = out;                // d_out doubles as z buffer
    float* c2raw = th_;                // theta dead after attention

    dim3 cgrid(2, 256);  // 2 h-tiles x (B*C)

    // conv1 (raw, pre-BN)
    conv3x3_k<1, false, false><<<cgrid, 256, 0, stream>>>(
        x, c1w, nullptr, nullptr, nullptr, nullptr, nullptr, nullptr, nullptr,
        c1raw, nullptr, nullptr);
    // BN1 stats
    bn_stats_k<<<64, 256, 0, stream>>>(c1raw, bn1g, bn1b, sc1, sh1);
    // theta/phi/g fused (BN1+ReLU applied to input on the fly)
    conv3x3_k<3, true, true><<<cgrid, 256, 0, stream>>>(
        c1raw, thw, phw, gw, thb, phb, gb, sc1, sh1, th_, ph_, g_);
    // flash attention
    attn_k<<<256, 256, 0, stream>>>(th_, ph_, g_, y_);
    // 1x1 conv + bias + residual -> z (in d_out)
    conv1x1_res_k<<<256, 256, 0, stream>>>(y_, Wwt, Wbs, x, z_);
    // conv2 (raw)
    conv3x3_k<1, false, false><<<cgrid, 256, 0, stream>>>(
        z_, c2w, nullptr, nullptr, nullptr, nullptr, nullptr, nullptr, nullptr,
        c2raw, nullptr, nullptr);
    // BN2 stats + apply + relu -> out
    bn_stats_k<<<64, 256, 0, stream>>>(c2raw, bn2g, bn2b, sc2, sh2);
    bn_relu_k<<<1024, 256, 0, stream>>>(c2raw, sc2, sh2, out);
}

// Round 2
// 422.764 us; speedup vs baseline: 3.0392x; 3.0392x over previous
//
#include <hip/hip_runtime.h>
#include <math.h>

// B=4, C=64, H=W=64, N=4096. All fp32 in/out.
//
// ws layout (floats), 5M + 256 total (same footprint as round 1):
//  A  = ws+0     : c1raw [1M]            -> after fused conv: thT_hi/thT_lo (bf16)
//  Bq = ws+1M    : theta fp32            -> after prep: yT (attn out, [B][N][C] fp32) -> c2raw
//  Cq = ws+2M    : phi fp32              -> after prep_tp: g16 (bf16 [B][C][N])
//  Dq = ws+3M    : g fp32
//  Eq = ws+4M    : phT_hi/phT_lo (bf16 [B][N][C])
//  F  = ws+5M    : stats (sc1,sh1,sc2,sh2)

typedef __attribute__((ext_vector_type(8))) short short8;
typedef __attribute__((ext_vector_type(4))) float f32x4;

__device__ __forceinline__ ushort f2bf(float x) {
    unsigned u = __float_as_uint(x);
    unsigned r = (u + 0x7FFFu + ((u >> 16) & 1u)) >> 16;  // RNE
    return (ushort)r;
}
__device__ __forceinline__ float bf2f(ushort h) {
    return __uint_as_float(((unsigned)h) << 16);
}

// ---------------------------------------------------------------------------
// 3x3 conv, pad 1. Block: 4 co x 16h x 64w tile. 256 thr: t>>4 = h, (t&15)*4 = w.
// Patch LDS: rows 18 (h0-1..h0+16), cols j=0..67 where j = col+1 (j=0 -> col -1
// always zero, j=65 -> col 64 always zero). Double-buffered, 1 barrier/ci.
// NOUT outputs share every patch read. BNIN applies relu(x*sc+sh) while staging
// (zero-pad stays zero, i.e. pad applied post-BN as in reference).
// ---------------------------------------------------------------------------
template <int NOUT, bool BNIN, bool BIAS>
__global__ __launch_bounds__(256) void conv3x3_k(
    const float* __restrict__ in,
    const float* __restrict__ w0c, const float* __restrict__ w1c,
    const float* __restrict__ w2c,
    const float* __restrict__ b0c, const float* __restrict__ b1c,
    const float* __restrict__ b2c,
    const float* __restrict__ bnsc, const float* __restrict__ bnsh,
    float* __restrict__ o0, float* __restrict__ o1, float* __restrict__ o2)
{
    __shared__ __align__(16) float patch[2][18 * 68];
    const int t   = threadIdx.x;
    const int b   = blockIdx.y >> 4;
    const int co0 = (blockIdx.y & 15) << 2;
    const int h0  = blockIdx.x << 4;
    const int h   = t >> 4;
    const int w4  = (t & 15) << 2;

    if (t < 36) {  // permanently-zero columns (written once, never overwritten)
        int r = t % 18, bu = t / 18;
        patch[bu][r * 68 + 0]  = 0.f;
        patch[bu][r * 68 + 65] = 0.f;
        patch[bu][r * 68 + 66] = 0.f;
        patch[bu][r * 68 + 67] = 0.f;
    }

    auto ldslot = [&](int ci, int s) -> float4 {
        int r = s >> 4, k = s & 15;
        int gr = h0 + r - 1;
        float4 v = make_float4(0.f, 0.f, 0.f, 0.f);
        if ((unsigned)gr < 64u) {
            v = *(const float4*)&in[(((size_t)(b * 64 + ci)) << 12) + (gr << 6) + (k << 2)];
            if (BNIN) {
                float sc = bnsc[ci], sh = bnsh[ci];
                v.x = fmaxf(v.x * sc + sh, 0.f);
                v.y = fmaxf(v.y * sc + sh, 0.f);
                v.z = fmaxf(v.z * sc + sh, 0.f);
                v.w = fmaxf(v.w * sc + sh, 0.f);
            }
        }
        return v;
    };
    auto stslot = [&](int bu, int s, float4 v) {
        int r = s >> 4, k = s & 15;
        float* p = &patch[bu][r * 68 + (k << 2) + 1];
        p[0] = v.x; p[1] = v.y; p[2] = v.z; p[3] = v.w;
    };

    float4 preA = ldslot(0, t);
    float4 preB;
    if (t < 32) preB = ldslot(0, 256 + t);
    stslot(0, t, preA);
    if (t < 32) stslot(0, 256 + t, preB);

    float acc[NOUT][4][4];
#pragma unroll
    for (int o = 0; o < NOUT; ++o)
#pragma unroll
        for (int c = 0; c < 4; ++c)
#pragma unroll
            for (int i = 0; i < 4; ++i) acc[o][c][i] = 0.f;

    const float* wsrc[3] = {w0c, w1c, w2c};

    for (int ci = 0; ci < 64; ++ci) {
        const int bu = ci & 1;
        if (ci + 1 < 64) {
            preA = ldslot(ci + 1, t);
            if (t < 32) preB = ldslot(ci + 1, 256 + t);
        }
        __syncthreads();  // patch[bu] ready; prior reads of patch[bu^1] done

        float vals[3][6];
#pragma unroll
        for (int kh = 0; kh < 3; ++kh) {
            const float* pr = &patch[bu][(h + kh) * 68 + w4];
            float4 Av = *(const float4*)pr;
            float2 Bv = *(const float2*)(pr + 4);
            vals[kh][0] = Av.x; vals[kh][1] = Av.y; vals[kh][2] = Av.z;
            vals[kh][3] = Av.w; vals[kh][4] = Bv.x; vals[kh][5] = Bv.y;
        }
#pragma unroll
        for (int o = 0; o < NOUT; ++o)
#pragma unroll
            for (int c = 0; c < 4; ++c) {
                const float* wb = wsrc[o] + ((size_t)(((co0 + c) << 6) + ci)) * 9;
#pragma unroll
                for (int kh = 0; kh < 3; ++kh) {
                    float W0 = wb[kh * 3 + 0], W1 = wb[kh * 3 + 1], W2 = wb[kh * 3 + 2];
#pragma unroll
                    for (int i = 0; i < 4; ++i)
                        acc[o][c][i] = fmaf(W0, vals[kh][i],
                                       fmaf(W1, vals[kh][i + 1],
                                       fmaf(W2, vals[kh][i + 2], acc[o][c][i])));
                }
            }
        if (ci + 1 < 64) {
            stslot(bu ^ 1, t, preA);
            if (t < 32) stslot(bu ^ 1, 256 + t, preB);
        }
    }

    const float* bsrc[3] = {b0c, b1c, b2c};
    float* osrc[3] = {o0, o1, o2};
#pragma unroll
    for (int o = 0; o < NOUT; ++o)
#pragma unroll
        for (int c = 0; c < 4; ++c) {
            float bias = BIAS ? bsrc[o][co0 + c] : 0.f;
            float4 v = make_float4(acc[o][c][0] + bias, acc[o][c][1] + bias,
                                   acc[o][c][2] + bias, acc[o][c][3] + bias);
            *(float4*)&osrc[o][(((size_t)(b * 64 + co0 + c)) << 12) +
                               ((h0 + h) << 6) + w4] = v;
        }
}

// ---------------------------------------------------------------------------
// BN stats (training-mode, biased var): scale/shift per channel.
// ---------------------------------------------------------------------------
__global__ __launch_bounds__(256) void bn_stats_k(
    const float* __restrict__ in, const float* __restrict__ gamma,
    const float* __restrict__ beta, float* __restrict__ scale,
    float* __restrict__ shift)
{
    const int c = blockIdx.x;
    const int t = threadIdx.x;
    float s = 0.f, ss = 0.f;
    for (int p = t; p < 4096; p += 256) {
        int bidx = p >> 10;
        int n4 = (p & 1023) << 2;
        float4 v = *(const float4*)&in[(((size_t)(bidx * 64 + c)) << 12) + n4];
        s += v.x + v.y + v.z + v.w;
        ss += v.x * v.x + v.y * v.y + v.z * v.z + v.w * v.w;
    }
#pragma unroll
    for (int off = 32; off > 0; off >>= 1) {
        s += __shfl_down(s, off);
        ss += __shfl_down(ss, off);
    }
    __shared__ float red[8];
    const int wid = t >> 6;
    if ((t & 63) == 0) { red[wid] = s; red[wid + 4] = ss; }
    __syncthreads();
    if (t == 0) {
        float S = red[0] + red[1] + red[2] + red[3];
        float SS = red[4] + red[5] + red[6] + red[7];
        float mean = S * (1.f / 16384.f);
        float var = SS * (1.f / 16384.f) - mean * mean;
        float sc = gamma[c] * rsqrtf(var + 1e-5f);
        scale[c] = sc;
        shift[c] = beta[c] - mean * sc;
    }
}

// ---------------------------------------------------------------------------
// prep_tp: theta,phi fp32 [B][C][N] -> transposed bf16 hi/lo [B][N][C].
// hi = bf16(v), lo = bf16(v - hi) for the 3-MFMA error-compensated QK^T.
// ---------------------------------------------------------------------------
__global__ __launch_bounds__(256) void prep_tp_k(
    const float* __restrict__ theta, const float* __restrict__ phi,
    ushort* __restrict__ thT_hi, ushort* __restrict__ thT_lo,
    ushort* __restrict__ phT_hi, ushort* __restrict__ phT_lo)
{
    __shared__ __align__(16) float Tt[64 * 68];
    __shared__ __align__(16) float Tp[64 * 68];
    const int b = blockIdx.x >> 6, n0 = (blockIdx.x & 63) << 6, t = threadIdx.x;
    for (int p = t; p < 1024; p += 256) {
        int c = p >> 4, n4 = (p & 15) << 2;
        *(float4*)&Tt[c * 68 + n4] =
            *(const float4*)&theta[(((size_t)(b * 64 + c)) << 12) + n0 + n4];
        *(float4*)&Tp[c * 68 + n4] =
            *(const float4*)&phi[(((size_t)(b * 64 + c)) << 12) + n0 + n4];
    }
    __syncthreads();
    for (int p = t; p < 1024; p += 256) {
        int n = p >> 4, c4 = (p & 15) << 2;
        size_t o = (((size_t)(b * 4096 + n0 + n)) << 6) + c4;
        ushort4 hi, lo;
        float v;
        v = Tt[(c4 + 0) * 68 + n]; hi.x = f2bf(v); lo.x = f2bf(v - bf2f(hi.x));
        v = Tt[(c4 + 1) * 68 + n]; hi.y = f2bf(v); lo.y = f2bf(v - bf2f(hi.y));
        v = Tt[(c4 + 2) * 68 + n]; hi.z = f2bf(v); lo.z = f2bf(v - bf2f(hi.z));
        v = Tt[(c4 + 3) * 68 + n]; hi.w = f2bf(v); lo.w = f2bf(v - bf2f(hi.w));
        *(ushort4*)&thT_hi[o] = hi; *(ushort4*)&thT_lo[o] = lo;
        v = Tp[(c4 + 0) * 68 + n]; hi.x = f2bf(v); lo.x = f2bf(v - bf2f(hi.x));
        v = Tp[(c4 + 1) * 68 + n]; hi.y = f2bf(v); lo.y = f2bf(v - bf2f(hi.y));
        v = Tp[(c4 + 2) * 68 + n]; hi.z = f2bf(v); lo.z = f2bf(v - bf2f(hi.z));
        v = Tp[(c4 + 3) * 68 + n]; hi.w = f2bf(v); lo.w = f2bf(v - bf2f(hi.w));
        *(ushort4*)&phT_hi[o] = hi; *(ushort4*)&phT_lo[o] = lo;
    }
}

// g fp32 [B][C][N] -> bf16 same layout.
__global__ __launch_bounds__(256) void prep_g_k(
    const float* __restrict__ g, ushort* __restrict__ g16)
{
    size_t p = (size_t)blockIdx.x * 256 + threadIdx.x;  // 262144 float4 groups
    float4 v = *(const float4*)&g[p << 2];
    ushort4 r;
    r.x = f2bf(v.x); r.y = f2bf(v.y); r.z = f2bf(v.z); r.w = f2bf(v.w);
    *(ushort4*)&g16[p << 2] = r;
}

// ---------------------------------------------------------------------------
// Flash attention, bf16 MFMA 16x16x32, static max M=30 (no rescale).
// S = thT x phT^T via hi/lo split (3 MFMAs); P = exp(S-30) bf16 via LDS;
// O += P x V; l += P x ones (extra MFMA). Q-tile 64, KV-tile 64, 64 steps.
// LDS tiles are [row][8 x 16B-chunks] with chunk ^= (row&7) XOR swizzle:
// conflict-free b128 frag reads. K single-buffered (written in PV phase),
// V/P correctly double/hazard-buffered. 2 barriers/step. 56 KB LDS.
// Output yT [B][N][C] fp32.
// ---------------------------------------------------------------------------
__device__ __forceinline__ short8 ldfrag(const ushort* base, int row, int ch) {
    return *(const short8*)&base[(row << 6) + (((ch ^ (row & 7))) << 3)];
}

__global__ __launch_bounds__(256) void attn_k(
    const ushort* __restrict__ thT_hi, const ushort* __restrict__ thT_lo,
    const ushort* __restrict__ phT_hi, const ushort* __restrict__ phT_lo,
    const ushort* __restrict__ g16, float* __restrict__ yT)
{
    __shared__ __align__(16) ushort Qhi[4096], Qlo[4096], Khi[4096], Klo[4096];
    __shared__ __align__(16) ushort Vt[2][4096];
    __shared__ __align__(16) ushort Pt[4096];

    const int t     = threadIdx.x;
    const int b     = blockIdx.x >> 6;
    const int q0    = (blockIdx.x & 63) << 6;
    const int lane  = t & 63;
    const int wv    = t >> 6;
    const int quad  = lane >> 4;
    const int l15   = lane & 15;
    const int rhalf = (wv >> 1) << 5;
    const int chalf = (wv & 1) << 5;

    const size_t cb64 = ((size_t)b) << 18;  // b*4096*64
    const ushort* Qh_g = thT_hi + cb64 + (((size_t)q0) << 6);
    const ushort* Ql_g = thT_lo + cb64 + (((size_t)q0) << 6);
    const ushort* Kh_g = phT_hi + cb64;
    const ushort* Kl_g = phT_lo + cb64;
    const ushort* Vg   = g16 + cb64;

    // initial staging: Q tiles + step-0 K/V
#pragma unroll
    for (int rd = 0; rd < 2; ++rd) {
        int ii = rd * 256 + t;
        int row = ii >> 3, ch = ii & 7;
        int off = (row << 6) + ((ch ^ (row & 7)) << 3);
        *(short8*)&Qhi[off] = *(const short8*)&Qh_g[ii << 3];
        *(short8*)&Qlo[off] = *(const short8*)&Ql_g[ii << 3];
        *(short8*)&Khi[off] = *(const short8*)&Kh_g[ii << 3];
        *(short8*)&Klo[off] = *(const short8*)&Kl_g[ii << 3];
        *(short8*)&Vt[0][off] = *(const short8*)&Vg[(row << 12) + (ch << 3)];
    }

    f32x4 oacc[2][2];
    f32x4 lacc[2];
#pragma unroll
    for (int rb = 0; rb < 2; ++rb) {
#pragma unroll
        for (int j = 0; j < 4; ++j) lacc[rb][j] = 0.f;
#pragma unroll
        for (int cb = 0; cb < 2; ++cb)
#pragma unroll
            for (int j = 0; j < 4; ++j) oacc[rb][cb][j] = 0.f;
    }
    short8 onesB;
    {
        short ov = (l15 == 0) ? (short)0x3F80 : (short)0;
#pragma unroll
        for (int j = 0; j < 8; ++j) onesB[j] = ov;
    }

    for (int step = 0; step < 64; ++step) {
        const int buf = step & 1;
        __syncthreads();  // B1: K/V(step) visible; P(step-1) consumers done

        short8 rKh[2], rKl[2], rV[2];
        if (step < 63) {
            const int m1 = (step + 1) << 6;
#pragma unroll
            for (int rd = 0; rd < 2; ++rd) {
                int ii = rd * 256 + t;
                int row = ii >> 3, ch = ii & 7;
                rKh[rd] = *(const short8*)&Kh_g[((m1 + row) << 6) + (ch << 3)];
                rKl[rd] = *(const short8*)&Kl_g[((m1 + row) << 6) + (ch << 3)];
                rV[rd]  = *(const short8*)&Vg[(row << 12) + m1 + (ch << 3)];
            }
        }

        // ---- phase 1: S = Q K^T (hi/lo compensated), exp, P write
        short8 aHi[2][2], aLo[2][2], bHi[2][2], bLo[2][2];
#pragma unroll
        for (int rb = 0; rb < 2; ++rb) {
            int row = rhalf + (rb << 4) + l15;
#pragma unroll
            for (int ks = 0; ks < 2; ++ks) {
                aHi[rb][ks] = ldfrag(Qhi, row, (ks << 2) + quad);
                aLo[rb][ks] = ldfrag(Qlo, row, (ks << 2) + quad);
            }
        }
#pragma unroll
        for (int cb = 0; cb < 2; ++cb) {
            int row = chalf + (cb << 4) + l15;
#pragma unroll
            for (int ks = 0; ks < 2; ++ks) {
                bHi[cb][ks] = ldfrag(Khi, row, (ks << 2) + quad);
                bLo[cb][ks] = ldfrag(Klo, row, (ks << 2) + quad);
            }
        }
        f32x4 sacc[2][2];
#pragma unroll
        for (int rb = 0; rb < 2; ++rb)
#pragma unroll
            for (int cb = 0; cb < 2; ++cb)
#pragma unroll
                for (int j = 0; j < 4; ++j) sacc[rb][cb][j] = 0.f;
#pragma unroll
        for (int ks = 0; ks < 2; ++ks)
#pragma unroll
            for (int rb = 0; rb < 2; ++rb)
#pragma unroll
                for (int cb = 0; cb < 2; ++cb) {
                    sacc[rb][cb] = __builtin_amdgcn_mfma_f32_16x16x32_bf16(
                        aHi[rb][ks], bHi[cb][ks], sacc[rb][cb], 0, 0, 0);
                    sacc[rb][cb] = __builtin_amdgcn_mfma_f32_16x16x32_bf16(
                        aHi[rb][ks], bLo[cb][ks], sacc[rb][cb], 0, 0, 0);
                    sacc[rb][cb] = __builtin_amdgcn_mfma_f32_16x16x32_bf16(
                        aLo[rb][ks], bHi[cb][ks], sacc[rb][cb], 0, 0, 0);
                }
#pragma unroll
        for (int rb = 0; rb < 2; ++rb)
#pragma unroll
            for (int cb = 0; cb < 2; ++cb) {
                int pcol = chalf + (cb << 4) + l15;
#pragma unroll
                for (int r = 0; r < 4; ++r) {
                    int prow = rhalf + (rb << 4) + (quad << 2) + r;
                    float p = __expf(sacc[rb][cb][r] - 30.f);
                    Pt[(prow << 6) + (((pcol >> 3) ^ (prow & 7)) << 3) + (pcol & 7)]
                        = f2bf(p);
                }
            }
        __syncthreads();  // B2: P visible; all S-phase K reads done

        // ---- phase 2: O += P V, l += P·1, stage K/V(step+1)
        short8 pa[2][2], vb[2][2];
#pragma unroll
        for (int rb = 0; rb < 2; ++rb) {
            int row = rhalf + (rb << 4) + l15;
#pragma unroll
            for (int ks = 0; ks < 2; ++ks)
                pa[rb][ks] = ldfrag(Pt, row, (ks << 2) + quad);
        }
#pragma unroll
        for (int cb = 0; cb < 2; ++cb) {
            int row = chalf + (cb << 4) + l15;
#pragma unroll
            for (int ks = 0; ks < 2; ++ks)
                vb[cb][ks] = ldfrag(&Vt[buf][0], row, (ks << 2) + quad);
        }
#pragma unroll
        for (int ks = 0; ks < 2; ++ks)
#pragma unroll
            for (int rb = 0; rb < 2; ++rb)
#pragma unroll
                for (int cb = 0; cb < 2; ++cb)
                    oacc[rb][cb] = __builtin_amdgcn_mfma_f32_16x16x32_bf16(
                        pa[rb][ks], vb[cb][ks], oacc[rb][cb], 0, 0, 0);
#pragma unroll
        for (int rb = 0; rb < 2; ++rb)
#pragma unroll
            for (int ks = 0; ks < 2; ++ks)
                lacc[rb] = __builtin_amdgcn_mfma_f32_16x16x32_bf16(
                    pa[rb][ks], onesB, lacc[rb], 0, 0, 0);

        if (step < 63) {
#pragma unroll
            for (int rd = 0; rd < 2; ++rd) {
                int ii = rd * 256 + t;
                int row = ii >> 3, ch = ii & 7;
                int off = (row << 6) + ((ch ^ (row & 7)) << 3);
                *(short8*)&Khi[off] = rKh[rd];
                *(short8*)&Klo[off] = rKl[rd];
                *(short8*)&Vt[buf ^ 1][off] = rV[rd];
            }
        }
    }

    // epilogue: divide by l, write yT[b][n][c]
#pragma unroll
    for (int rb = 0; rb < 2; ++rb) {
        float linv[4];
#pragma unroll
        for (int r = 0; r < 4; ++r)
            linv[r] = 1.f / __shfl(lacc[rb][r], lane & 48);
#pragma unroll
        for (int cb = 0; cb < 2; ++cb) {
            int cc = chalf + (cb << 4) + l15;
#pragma unroll
            for (int r = 0; r < 4; ++r) {
                int nn = q0 + rhalf + (rb << 4) + (quad << 2) + r;
                yT[cb64 + (((size_t)nn) << 6) + cc] = oacc[rb][cb][r] * linv[r];
            }
        }
    }
}

// ---------------------------------------------------------------------------
// z = W(1x1)*y + Wb + x. y given transposed (yT [B][N][C]); LDS-transpose it.
// ---------------------------------------------------------------------------
__global__ __launch_bounds__(256) void conv1x1_res_k(
    const float* __restrict__ yT, const float* __restrict__ Wmat,
    const float* __restrict__ Wb, const float* __restrict__ x,
    float* __restrict__ z)
{
    __shared__ __align__(16) float Wt[64 * 68];  // [ci][co]
    __shared__ __align__(16) float Ys[64 * 68];  // [ci][n]
    const int b  = blockIdx.x >> 6;
    const int n0 = (blockIdx.x & 63) << 6;
    const int t  = threadIdx.x;
    const int i4 = (t >> 4) << 2;
    const int j4 = (t & 15) << 2;

    for (int p = t; p < 4096; p += 256) {
        int co = p >> 6, ci = p & 63;
        Wt[ci * 68 + co] = Wmat[p];
    }
    for (int p = t; p < 1024; p += 256) {
        int nr = p >> 4, c4 = (p & 15) << 2;
        float4 v = *(const float4*)&yT[(((size_t)(b * 4096 + n0 + nr)) << 6) + c4];
        Ys[(c4 + 0) * 68 + nr] = v.x;
        Ys[(c4 + 1) * 68 + nr] = v.y;
        Ys[(c4 + 2) * 68 + nr] = v.z;
        Ys[(c4 + 3) * 68 + nr] = v.w;
    }
    __syncthreads();

    float acc[4][4];
#pragma unroll
    for (int a = 0; a < 4; ++a)
#pragma unroll
        for (int bb = 0; bb < 4; ++bb) acc[a][bb] = 0.f;

#pragma unroll 4
    for (int ci = 0; ci < 64; ++ci) {
        float4 w = *(const float4*)&Wt[ci * 68 + i4];
        float4 yv = *(const float4*)&Ys[ci * 68 + j4];
        float wa[4] = {w.x, w.y, w.z, w.w};
        float ya[4] = {yv.x, yv.y, yv.z, yv.w};
#pragma unroll
        for (int a = 0; a < 4; ++a)
#pragma unroll
            for (int bb = 0; bb < 4; ++bb)
                acc[a][bb] = fmaf(wa[a], ya[bb], acc[a][bb]);
    }
#pragma unroll
    for (int a = 0; a < 4; ++a) {
        int co = i4 + a;
        size_t base = (((size_t)(b * 64 + co)) << 12) + n0 + j4;
        float4 xv = *(const float4*)&x[base];
        float bias = Wb[co];
        float4 r = make_float4(acc[a][0] + bias + xv.x, acc[a][1] + bias + xv.y,
                               acc[a][2] + bias + xv.z, acc[a][3] + bias + xv.w);
        *(float4*)&z[base] = r;
    }
}

// ---------------------------------------------------------------------------
__global__ __launch_bounds__(256) void bn_relu_k(
    const float* __restrict__ in, const float* __restrict__ scale,
    const float* __restrict__ shift, float* __restrict__ out)
{
    int p = blockIdx.x * 256 + threadIdx.x;
    int c = (p >> 10) & 63;
    float sc = scale[c], sh = shift[c];
    float4 v = *(const float4*)&in[(size_t)p << 2];
    float4 r = make_float4(fmaxf(v.x * sc + sh, 0.f), fmaxf(v.y * sc + sh, 0.f),
                           fmaxf(v.z * sc + sh, 0.f), fmaxf(v.w * sc + sh, 0.f));
    *(float4*)&out[(size_t)p << 2] = r;
}

// ---------------------------------------------------------------------------
extern "C" void kernel_launch(void* const* d_in, const int* in_sizes, int n_in,
                              void* d_out, int out_size, void* d_ws,
                              size_t ws_size, hipStream_t stream)
{
    const float* x    = (const float*)d_in[0];
    const float* c1w  = (const float*)d_in[1];
    const float* bn1g = (const float*)d_in[2];
    const float* bn1b = (const float*)d_in[3];
    const float* thw  = (const float*)d_in[4];
    const float* thb  = (const float*)d_in[5];
    const float* phw  = (const float*)d_in[6];
    const float* phb  = (const float*)d_in[7];
    const float* gw   = (const float*)d_in[8];
    const float* gb   = (const float*)d_in[9];
    const float* Wwt  = (const float*)d_in[10];
    const float* Wbs  = (const float*)d_in[11];
    const float* c2w  = (const float*)d_in[12];
    const float* bn2g = (const float*)d_in[13];
    const float* bn2b = (const float*)d_in[14];
    float* out = (float*)d_out;

    float* ws    = (float*)d_ws;
    float* c1raw = ws;                  // A
    float* theta = ws + (1 << 20);      // Bq
    float* phi   = ws + (2 << 20);      // Cq
    float* g_    = ws + (3 << 20);      // Dq
    float* stats = ws + (5 << 20);      // F
    ushort* thT_hi = (ushort*)ws;                         // A (c1raw dead)
    ushort* thT_lo = (ushort*)(ws + (1 << 19));
    ushort* phT_hi = (ushort*)(ws + (4 << 20));           // Eq
    ushort* phT_lo = (ushort*)(ws + (4 << 20) + (1 << 19));
    ushort* g16    = (ushort*)phi;                        // Cq (phi dead)
    float* yT    = theta;               // Bq (theta dead after prep)
    float* c2raw = theta;               // Bq (yT dead after conv1x1)
    float* sc1 = stats, *sh1 = stats + 64, *sc2 = stats + 128, *sh2 = stats + 192;

    dim3 cgrid(4, 64);  // 4 h-tiles x (16 co-groups * 4 b)

    conv3x3_k<1, false, false><<<cgrid, 256, 0, stream>>>(
        x, c1w, nullptr, nullptr, nullptr, nullptr, nullptr, nullptr, nullptr,
        c1raw, nullptr, nullptr);
    bn_stats_k<<<64, 256, 0, stream>>>(c1raw, bn1g, bn1b, sc1, sh1);
    conv3x3_k<3, true, true><<<cgrid, 256, 0, stream>>>(
        c1raw, thw, phw, gw, thb, phb, gb, sc1, sh1, theta, phi, g_);
    prep_tp_k<<<256, 256, 0, stream>>>(theta, phi, thT_hi, thT_lo, phT_hi, phT_lo);
    prep_g_k<<<1024, 256, 0, stream>>>(g_, g16);
    attn_k<<<256, 256, 0, stream>>>(thT_hi, thT_lo, phT_hi, phT_lo, g16, yT);
    conv1x1_res_k<<<256, 256, 0, stream>>>(yT, Wwt, Wbs, x, out);
    conv3x3_k<1, false, false><<<cgrid, 256, 0, stream>>>(
        out, c2w, nullptr, nullptr, nullptr, nullptr, nullptr, nullptr, nullptr,
        c2raw, nullptr, nullptr);
    bn_stats_k<<<64, 256, 0, stream>>>(c2raw, bn2g, bn2b, sc2, sh2);
    bn_relu_k<<<1024, 256, 0, stream>>>(c2raw, sc2, sh2, out);
}

// Round 3
// 271.812 us; speedup vs baseline: 4.7270x; 1.5554x over previous
//
#include <hip/hip_runtime.h>
#include <math.h>

// B=4, C=64, H=W=64, N=4096, NPIX=16384. All fp32 in/out.
//
// Pipeline lives in pixel-major [pix][ch] bf16 hi/lo layout (pix = b*4096+h*64+w).
// ws (floats), proven footprint 5M+256:
//  region A ws+0M..1M : xT hi|lo  -> x1T hi|lo -> zT hi|lo   (each array 1M ushorts)
//  region B ws+1M..2M : c1T fp32  -> yT hi|lo
//  region C ws+2M..3M : thT hi|lo -> c2T fp32
//  region D ws+3M..4M : phT hi|lo
//  region E ws+4M..4.5M : g16 (bf16 [B][C][N])
//  wp at ws+4.5M : prepped weights (5x 3x3 sets + 1x1), bf16 hi/lo
//  part at ws+5M-33024 ; stats at ws+5M (sc1,sh1,sc2,sh2)

typedef __attribute__((ext_vector_type(8))) short short8;
typedef __attribute__((ext_vector_type(4))) float f32x4;

__device__ __forceinline__ ushort f2bf(float x) {
    unsigned u = __float_as_uint(x);
    unsigned r = (u + 0x7FFFu + ((u >> 16) & 1u)) >> 16;  // RNE
    return (ushort)r;
}
__device__ __forceinline__ float bf2f(ushort h) {
    return __uint_as_float(((unsigned)h) << 16);
}

// ---------------------------------------------------------------------------
// Weight prep: 5 sets of 3x3 weights [co][ci][3][3] -> [tap][co][ci] bf16 hi/lo,
// plus the 1x1 set [co][ci] -> [co][ci] hi/lo. One launch, grid (144, 6).
// ---------------------------------------------------------------------------
__global__ __launch_bounds__(256) void wprep_k(
    const float* __restrict__ w0, const float* __restrict__ w1,
    const float* __restrict__ w2, const float* __restrict__ w3,
    const float* __restrict__ w4, const float* __restrict__ w5,
    ushort* __restrict__ base)
{
    const float* W[6] = {w0, w1, w2, w3, w4, w5};
    int s = blockIdx.y;
    int idx = blockIdx.x * 256 + threadIdx.x;
    if (s < 5) {
        if (idx >= 36864) return;
        int co = idx / 576;
        int r = idx - co * 576;
        int ci = r / 9;
        int tap = r - ci * 9;  // kh*3+kw
        float v = W[s][idx];
        ushort* hi = base + (size_t)s * 73728;
        ushort* lo = hi + 36864;
        int off = tap * 4096 + co * 64 + ci;
        ushort h = f2bf(v);
        hi[off] = h;
        lo[off] = f2bf(v - bf2f(h));
    } else {
        if (idx >= 4096) return;
        float v = W[5][idx];
        ushort* hi = base + 5 * 73728;
        ushort* lo = hi + 4096;
        ushort h = f2bf(v);
        hi[idx] = h;
        lo[idx] = f2bf(v - bf2f(h));
    }
}

// ---------------------------------------------------------------------------
// prep0: x [B][C][N] fp32 -> xT [pix][ch] bf16 hi/lo (LDS transpose).
// ---------------------------------------------------------------------------
__global__ __launch_bounds__(256) void prep0_k(
    const float* __restrict__ x, ushort* __restrict__ xh, ushort* __restrict__ xl)
{
    __shared__ __align__(16) float T[64 * 68];
    const int b = blockIdx.x >> 6, n0 = (blockIdx.x & 63) << 6, t = threadIdx.x;
    for (int p = t; p < 1024; p += 256) {
        int c = p >> 4, n4 = (p & 15) << 2;
        *(float4*)&T[c * 68 + n4] =
            *(const float4*)&x[(((size_t)(b * 64 + c)) << 12) + n0 + n4];
    }
    __syncthreads();
    for (int p = t; p < 1024; p += 256) {
        int n = p >> 4, c4 = (p & 15) << 2;
        size_t off = (((size_t)(b * 4096 + n0 + n)) << 6) + c4;
        ushort4 hi, lo;
        float v;
        v = T[(c4 + 0) * 68 + n]; hi.x = f2bf(v); lo.x = f2bf(v - bf2f(hi.x));
        v = T[(c4 + 1) * 68 + n]; hi.y = f2bf(v); lo.y = f2bf(v - bf2f(hi.y));
        v = T[(c4 + 2) * 68 + n]; hi.z = f2bf(v); lo.z = f2bf(v - bf2f(hi.z));
        v = T[(c4 + 3) * 68 + n]; hi.w = f2bf(v); lo.w = f2bf(v - bf2f(hi.w));
        *(ushort4*)&xh[off] = hi;
        *(ushort4*)&xl[off] = lo;
    }
}

// ---------------------------------------------------------------------------
// MFMA 3x3 conv via 9 shifted 64x64 GEMM taps. Block = 64 pix (one h-row) x
// 64 co, 4 waves, wave tile 32pix x 32co. NO LDS, NO barriers: A-frags
// (rows=pixels, k=ci) and B-frags (rows=co, k=ci) stream from global (L2-hot).
// hi/lo error-compensated (3 MFMAs/product). MODE 0: fp32 out [pix][co].
// MODE 1 (NOUT=3): theta->hi/lo, phi->hi/lo [pix][co]; g->bf16 [B][co][n].
// ---------------------------------------------------------------------------
template <int NOUT, int MODE>
__global__ __launch_bounds__(256) void conv_mfma_k(
    const ushort* __restrict__ Ah, const ushort* __restrict__ Al,
    const ushort* __restrict__ w0h, const ushort* __restrict__ w0l,
    const ushort* __restrict__ w1h, const ushort* __restrict__ w1l,
    const ushort* __restrict__ w2h, const ushort* __restrict__ w2l,
    const float* __restrict__ b0, const float* __restrict__ b1,
    const float* __restrict__ b2,
    float* __restrict__ outF,
    ushort* __restrict__ o0h, ushort* __restrict__ o0l,
    ushort* __restrict__ o1h, ushort* __restrict__ o1l,
    ushort* __restrict__ o2t)
{
    const int t = threadIdx.x, lane = t & 63, wv = t >> 6;
    const int quad = lane >> 4, l15 = lane & 15;
    const int rhalf = (wv >> 1) << 5, chalf = (wv & 1) << 5;
    const int blk = blockIdx.x;  // b*64 + h
    const int h = blk & 63;
    const int P0 = blk << 6;

    const ushort* wh[3] = {w0h, w1h, w2h};
    const ushort* wl[3] = {w0l, w1l, w2l};

    f32x4 acc[NOUT][2][2];
#pragma unroll
    for (int o = 0; o < NOUT; ++o)
#pragma unroll
        for (int rb = 0; rb < 2; ++rb)
#pragma unroll
            for (int cb = 0; cb < 2; ++cb)
#pragma unroll
                for (int j = 0; j < 4; ++j) acc[o][rb][cb][j] = 0.f;

#pragma unroll
    for (int dh = -1; dh <= 1; ++dh) {
        if ((unsigned)(h + dh) >= 64u) continue;  // block-uniform
#pragma unroll
        for (int dw = -1; dw <= 1; ++dw) {
            const int tap = (dh + 1) * 3 + (dw + 1);
#pragma unroll
            for (int kc = 0; kc < 2; ++kc) {
                const int k0 = kc * 32 + quad * 8;
                short8 aH[2], aL[2];
#pragma unroll
                for (int rb = 0; rb < 2; ++rb) {
                    int wrow = rhalf + (rb << 4) + l15;  // w coord 0..63
                    int sw = wrow + dw;
                    short8 z = {0, 0, 0, 0, 0, 0, 0, 0};
                    aH[rb] = z;
                    aL[rb] = z;
                    if ((unsigned)sw < 64u) {
                        int sp = P0 + dh * 64 + sw;
                        size_t off = (((size_t)sp) << 6) + k0;
                        aH[rb] = *(const short8*)&Ah[off];
                        aL[rb] = *(const short8*)&Al[off];
                    }
                }
#pragma unroll
                for (int o = 0; o < NOUT; ++o) {
#pragma unroll
                    for (int cb = 0; cb < 2; ++cb) {
                        int co = chalf + (cb << 4) + l15;
                        size_t woff = (((size_t)tap) << 12) + (((size_t)co) << 6) + k0;
                        short8 bH = *(const short8*)&wh[o][woff];
                        short8 bL = *(const short8*)&wl[o][woff];
#pragma unroll
                        for (int rb = 0; rb < 2; ++rb) {
                            acc[o][rb][cb] = __builtin_amdgcn_mfma_f32_16x16x32_bf16(
                                aH[rb], bH, acc[o][rb][cb], 0, 0, 0);
                            acc[o][rb][cb] = __builtin_amdgcn_mfma_f32_16x16x32_bf16(
                                aH[rb], bL, acc[o][rb][cb], 0, 0, 0);
                            acc[o][rb][cb] = __builtin_amdgcn_mfma_f32_16x16x32_bf16(
                                aL[rb], bH, acc[o][rb][cb], 0, 0, 0);
                        }
                    }
                }
            }
        }
    }

    if (MODE == 0) {
#pragma unroll
        for (int rb = 0; rb < 2; ++rb)
#pragma unroll
            for (int cb = 0; cb < 2; ++cb) {
                int co = chalf + (cb << 4) + l15;
#pragma unroll
                for (int r = 0; r < 4; ++r) {
                    int pix = P0 + rhalf + (rb << 4) + (quad << 2) + r;
                    outF[(((size_t)pix) << 6) + co] = acc[0][rb][cb][r];
                }
            }
    } else {
        const int b = P0 >> 12;
#pragma unroll
        for (int rb = 0; rb < 2; ++rb)
#pragma unroll
            for (int cb = 0; cb < 2; ++cb) {
                int co = chalf + (cb << 4) + l15;
                float bth = b0[co], bph = b1[co], bg = b2[co];
                int pixb = P0 + rhalf + (rb << 4) + (quad << 2);
#pragma unroll
                for (int r = 0; r < 4; ++r) {
                    size_t off = (((size_t)(pixb + r)) << 6) + co;
                    float v = acc[0][rb][cb][r] + bth;
                    ushort hh = f2bf(v);
                    o0h[off] = hh;
                    o0l[off] = f2bf(v - bf2f(hh));
                    v = acc[1][rb][cb][r] + bph;
                    hh = f2bf(v);
                    o1h[off] = hh;
                    o1l[off] = f2bf(v - bf2f(hh));
                }
                int n0 = pixb & 4095;
                ushort4 gv;
                gv.x = f2bf(acc[2][rb][cb][0] + bg);
                gv.y = f2bf(acc[2][rb][cb][1] + bg);
                gv.z = f2bf(acc[2][rb][cb][2] + bg);
                gv.w = f2bf(acc[2][rb][cb][3] + bg);
                *(ushort4*)&o2t[(((size_t)b) << 18) + (((size_t)co) << 12) + n0] = gv;
            }
    }
}

// ---------------------------------------------------------------------------
// BN stats, two-phase deterministic. Phase A: 256 blocks x 64 pix each,
// lane = channel (coalesced 256B rows). Phase B: 1 block, 64 threads.
// ---------------------------------------------------------------------------
__global__ __launch_bounds__(256) void bnstatA_k(
    const float* __restrict__ src, float* __restrict__ part)
{
    const int t = threadIdx.x, lane = t & 63, wv = t >> 6;
    const int px0 = blockIdx.x * 64 + wv * 16;
    float s = 0.f, ss = 0.f;
    for (int i = 0; i < 16; ++i) {
        float v = src[(((size_t)(px0 + i)) << 6) + lane];
        s += v;
        ss += v * v;
    }
    __shared__ float red[2][4][64];
    red[0][wv][lane] = s;
    red[1][wv][lane] = ss;
    __syncthreads();
    if (t < 64) {
        float S = red[0][0][t] + red[0][1][t] + red[0][2][t] + red[0][3][t];
        float SS = red[1][0][t] + red[1][1][t] + red[1][2][t] + red[1][3][t];
        part[blockIdx.x * 64 + t] = S;
        part[16384 + blockIdx.x * 64 + t] = SS;
    }
}

__global__ __launch_bounds__(64) void bnstatB_k(
    const float* __restrict__ part, const float* __restrict__ gamma,
    const float* __restrict__ beta, float* __restrict__ scale,
    float* __restrict__ shift)
{
    int c = threadIdx.x;
    float S = 0.f, SS = 0.f;
    for (int k = 0; k < 256; ++k) {
        S += part[k * 64 + c];
        SS += part[16384 + k * 64 + c];
    }
    float mean = S * (1.f / 16384.f);
    float var = SS * (1.f / 16384.f) - mean * mean;
    float sc = gamma[c] * rsqrtf(var + 1e-5f);
    scale[c] = sc;
    shift[c] = beta[c] - mean * sc;
}

// ---------------------------------------------------------------------------
// x1prep: c1T fp32 [pix][ch] -> relu(BN) -> x1T bf16 hi/lo same layout.
// ---------------------------------------------------------------------------
__global__ __launch_bounds__(256) void x1prep_k(
    const float* __restrict__ c1T, const float* __restrict__ sc,
    const float* __restrict__ sh, ushort* __restrict__ xh,
    ushort* __restrict__ xl)
{
    int p = blockIdx.x * 256 + threadIdx.x;  // < 262144
    int c4 = (p & 15) << 2;
    float4 v = *(const float4*)&c1T[(size_t)p << 2];
    float4 s4 = *(const float4*)&sc[c4];
    float4 h4 = *(const float4*)&sh[c4];
    float r0 = fmaxf(v.x * s4.x + h4.x, 0.f);
    float r1 = fmaxf(v.y * s4.y + h4.y, 0.f);
    float r2 = fmaxf(v.z * s4.z + h4.z, 0.f);
    float r3 = fmaxf(v.w * s4.w + h4.w, 0.f);
    ushort4 hi, lo;
    hi.x = f2bf(r0); lo.x = f2bf(r0 - bf2f(hi.x));
    hi.y = f2bf(r1); lo.y = f2bf(r1 - bf2f(hi.y));
    hi.z = f2bf(r2); lo.z = f2bf(r2 - bf2f(hi.z));
    hi.w = f2bf(r3); lo.w = f2bf(r3 - bf2f(hi.w));
    *(ushort4*)&xh[(size_t)p << 2] = hi;
    *(ushort4*)&xl[(size_t)p << 2] = lo;
}

// ---------------------------------------------------------------------------
// Flash attention (unchanged core from round 2; epilogue now writes y as
// bf16 hi/lo [pix][ch] for the MFMA 1x1 conv). Static max M=30.
// ---------------------------------------------------------------------------
__device__ __forceinline__ short8 ldfrag(const ushort* base, int row, int ch) {
    return *(const short8*)&base[(row << 6) + (((ch ^ (row & 7))) << 3)];
}

__global__ __launch_bounds__(256) void attn_k(
    const ushort* __restrict__ thT_hi, const ushort* __restrict__ thT_lo,
    const ushort* __restrict__ phT_hi, const ushort* __restrict__ phT_lo,
    const ushort* __restrict__ g16, ushort* __restrict__ yh,
    ushort* __restrict__ yl)
{
    __shared__ __align__(16) ushort Qhi[4096], Qlo[4096], Khi[4096], Klo[4096];
    __shared__ __align__(16) ushort Vt[2][4096];
    __shared__ __align__(16) ushort Pt[4096];

    const int t = threadIdx.x;
    const int b = blockIdx.x >> 6;
    const int q0 = (blockIdx.x & 63) << 6;
    const int lane = t & 63;
    const int wv = t >> 6;
    const int quad = lane >> 4;
    const int l15 = lane & 15;
    const int rhalf = (wv >> 1) << 5;
    const int chalf = (wv & 1) << 5;

    const size_t cb64 = ((size_t)b) << 18;
    const ushort* Qh_g = thT_hi + cb64 + (((size_t)q0) << 6);
    const ushort* Ql_g = thT_lo + cb64 + (((size_t)q0) << 6);
    const ushort* Kh_g = phT_hi + cb64;
    const ushort* Kl_g = phT_lo + cb64;
    const ushort* Vg = g16 + cb64;

#pragma unroll
    for (int rd = 0; rd < 2; ++rd) {
        int ii = rd * 256 + t;
        int row = ii >> 3, ch = ii & 7;
        int off = (row << 6) + ((ch ^ (row & 7)) << 3);
        *(short8*)&Qhi[off] = *(const short8*)&Qh_g[ii << 3];
        *(short8*)&Qlo[off] = *(const short8*)&Ql_g[ii << 3];
        *(short8*)&Khi[off] = *(const short8*)&Kh_g[ii << 3];
        *(short8*)&Klo[off] = *(const short8*)&Kl_g[ii << 3];
        *(short8*)&Vt[0][off] = *(const short8*)&Vg[(row << 12) + (ch << 3)];
    }

    f32x4 oacc[2][2];
    f32x4 lacc[2];
#pragma unroll
    for (int rb = 0; rb < 2; ++rb) {
#pragma unroll
        for (int j = 0; j < 4; ++j) lacc[rb][j] = 0.f;
#pragma unroll
        for (int cb = 0; cb < 2; ++cb)
#pragma unroll
            for (int j = 0; j < 4; ++j) oacc[rb][cb][j] = 0.f;
    }
    short8 onesB;
    {
        short ov = (l15 == 0) ? (short)0x3F80 : (short)0;
#pragma unroll
        for (int j = 0; j < 8; ++j) onesB[j] = ov;
    }

    for (int step = 0; step < 64; ++step) {
        const int buf = step & 1;
        __syncthreads();

        short8 rKh[2], rKl[2], rV[2];
        if (step < 63) {
            const int m1 = (step + 1) << 6;
#pragma unroll
            for (int rd = 0; rd < 2; ++rd) {
                int ii = rd * 256 + t;
                int row = ii >> 3, ch = ii & 7;
                rKh[rd] = *(const short8*)&Kh_g[((m1 + row) << 6) + (ch << 3)];
                rKl[rd] = *(const short8*)&Kl_g[((m1 + row) << 6) + (ch << 3)];
                rV[rd] = *(const short8*)&Vg[(row << 12) + m1 + (ch << 3)];
            }
        }

        short8 aHi[2][2], aLo[2][2], bHi[2][2], bLo[2][2];
#pragma unroll
        for (int rb = 0; rb < 2; ++rb) {
            int row = rhalf + (rb << 4) + l15;
#pragma unroll
            for (int ks = 0; ks < 2; ++ks) {
                aHi[rb][ks] = ldfrag(Qhi, row, (ks << 2) + quad);
                aLo[rb][ks] = ldfrag(Qlo, row, (ks << 2) + quad);
            }
        }
#pragma unroll
        for (int cb = 0; cb < 2; ++cb) {
            int row = chalf + (cb << 4) + l15;
#pragma unroll
            for (int ks = 0; ks < 2; ++ks) {
                bHi[cb][ks] = ldfrag(Khi, row, (ks << 2) + quad);
                bLo[cb][ks] = ldfrag(Klo, row, (ks << 2) + quad);
            }
        }
        f32x4 sacc[2][2];
#pragma unroll
        for (int rb = 0; rb < 2; ++rb)
#pragma unroll
            for (int cb = 0; cb < 2; ++cb)
#pragma unroll
                for (int j = 0; j < 4; ++j) sacc[rb][cb][j] = 0.f;
#pragma unroll
        for (int ks = 0; ks < 2; ++ks)
#pragma unroll
            for (int rb = 0; rb < 2; ++rb)
#pragma unroll
                for (int cb = 0; cb < 2; ++cb) {
                    sacc[rb][cb] = __builtin_amdgcn_mfma_f32_16x16x32_bf16(
                        aHi[rb][ks], bHi[cb][ks], sacc[rb][cb], 0, 0, 0);
                    sacc[rb][cb] = __builtin_amdgcn_mfma_f32_16x16x32_bf16(
                        aHi[rb][ks], bLo[cb][ks], sacc[rb][cb], 0, 0, 0);
                    sacc[rb][cb] = __builtin_amdgcn_mfma_f32_16x16x32_bf16(
                        aLo[rb][ks], bHi[cb][ks], sacc[rb][cb], 0, 0, 0);
                }
#pragma unroll
        for (int rb = 0; rb < 2; ++rb)
#pragma unroll
            for (int cb = 0; cb < 2; ++cb) {
                int pcol = chalf + (cb << 4) + l15;
#pragma unroll
                for (int r = 0; r < 4; ++r) {
                    int prow = rhalf + (rb << 4) + (quad << 2) + r;
                    float p = __expf(sacc[rb][cb][r] - 30.f);
                    Pt[(prow << 6) + (((pcol >> 3) ^ (prow & 7)) << 3) + (pcol & 7)]
                        = f2bf(p);
                }
            }
        __syncthreads();

        short8 pa[2][2], vb[2][2];
#pragma unroll
        for (int rb = 0; rb < 2; ++rb) {
            int row = rhalf + (rb << 4) + l15;
#pragma unroll
            for (int ks = 0; ks < 2; ++ks)
                pa[rb][ks] = ldfrag(Pt, row, (ks << 2) + quad);
        }
#pragma unroll
        for (int cb = 0; cb < 2; ++cb) {
            int row = chalf + (cb << 4) + l15;
#pragma unroll
            for (int ks = 0; ks < 2; ++ks)
                vb[cb][ks] = ldfrag(&Vt[buf][0], row, (ks << 2) + quad);
        }
#pragma unroll
        for (int ks = 0; ks < 2; ++ks)
#pragma unroll
            for (int rb = 0; rb < 2; ++rb)
#pragma unroll
                for (int cb = 0; cb < 2; ++cb)
                    oacc[rb][cb] = __builtin_amdgcn_mfma_f32_16x16x32_bf16(
                        pa[rb][ks], vb[cb][ks], oacc[rb][cb], 0, 0, 0);
#pragma unroll
        for (int rb = 0; rb < 2; ++rb)
#pragma unroll
            for (int ks = 0; ks < 2; ++ks)
                lacc[rb] = __builtin_amdgcn_mfma_f32_16x16x32_bf16(
                    pa[rb][ks], onesB, lacc[rb], 0, 0, 0);

        if (step < 63) {
#pragma unroll
            for (int rd = 0; rd < 2; ++rd) {
                int ii = rd * 256 + t;
                int row = ii >> 3, ch = ii & 7;
                int off = (row << 6) + ((ch ^ (row & 7)) << 3);
                *(short8*)&Khi[off] = rKh[rd];
                *(short8*)&Klo[off] = rKl[rd];
                *(short8*)&Vt[buf ^ 1][off] = rV[rd];
            }
        }
    }

#pragma unroll
    for (int rb = 0; rb < 2; ++rb) {
        float linv[4];
#pragma unroll
        for (int r = 0; r < 4; ++r)
            linv[r] = 1.f / __shfl(lacc[rb][r], lane & 48);
#pragma unroll
        for (int cb = 0; cb < 2; ++cb) {
            int cc = chalf + (cb << 4) + l15;
#pragma unroll
            for (int r = 0; r < 4; ++r) {
                int nn = q0 + rhalf + (rb << 4) + (quad << 2) + r;
                float v = oacc[rb][cb][r] * linv[r];
                size_t off = cb64 + (((size_t)nn) << 6) + cc;
                ushort hh = f2bf(v);
                yh[off] = hh;
                yl[off] = f2bf(v - bf2f(hh));
            }
        }
    }
}

// ---------------------------------------------------------------------------
// 1x1 conv + bias + residual, MFMA. z = W*y + Wb + x, output bf16 hi/lo
// [pix][ch] (conv2 input). Residual from original x: float4-coalesced.
// ---------------------------------------------------------------------------
__global__ __launch_bounds__(256) void conv1x1_k(
    const ushort* __restrict__ yh, const ushort* __restrict__ yl,
    const ushort* __restrict__ wh, const ushort* __restrict__ wl,
    const float* __restrict__ Wb, const float* __restrict__ x,
    ushort* __restrict__ zh, ushort* __restrict__ zl)
{
    const int t = threadIdx.x, lane = t & 63, wv = t >> 6;
    const int quad = lane >> 4, l15 = lane & 15;
    const int rhalf = (wv >> 1) << 5, chalf = (wv & 1) << 5;
    const int P0 = blockIdx.x << 6;

    f32x4 acc[2][2];
#pragma unroll
    for (int rb = 0; rb < 2; ++rb)
#pragma unroll
        for (int cb = 0; cb < 2; ++cb)
#pragma unroll
            for (int j = 0; j < 4; ++j) acc[rb][cb][j] = 0.f;

#pragma unroll
    for (int kc = 0; kc < 2; ++kc) {
        const int k0 = kc * 32 + quad * 8;
        short8 aH[2], aL[2];
#pragma unroll
        for (int rb = 0; rb < 2; ++rb) {
            size_t off = (((size_t)(P0 + rhalf + (rb << 4) + l15)) << 6) + k0;
            aH[rb] = *(const short8*)&yh[off];
            aL[rb] = *(const short8*)&yl[off];
        }
#pragma unroll
        for (int cb = 0; cb < 2; ++cb) {
            int co = chalf + (cb << 4) + l15;
            size_t woff = (((size_t)co) << 6) + k0;
            short8 bH = *(const short8*)&wh[woff];
            short8 bL = *(const short8*)&wl[woff];
#pragma unroll
            for (int rb = 0; rb < 2; ++rb) {
                acc[rb][cb] = __builtin_amdgcn_mfma_f32_16x16x32_bf16(
                    aH[rb], bH, acc[rb][cb], 0, 0, 0);
                acc[rb][cb] = __builtin_amdgcn_mfma_f32_16x16x32_bf16(
                    aH[rb], bL, acc[rb][cb], 0, 0, 0);
                acc[rb][cb] = __builtin_amdgcn_mfma_f32_16x16x32_bf16(
                    aL[rb], bH, acc[rb][cb], 0, 0, 0);
            }
        }
    }

    const int b = P0 >> 12;
#pragma unroll
    for (int rb = 0; rb < 2; ++rb)
#pragma unroll
        for (int cb = 0; cb < 2; ++cb) {
            int co = chalf + (cb << 4) + l15;
            float bias = Wb[co];
            int pixb = P0 + rhalf + (rb << 4) + (quad << 2);
            int n0 = pixb & 4095;
            float4 xr = *(const float4*)&x[(((size_t)(b * 64 + co)) << 12) + n0];
            float xa[4] = {xr.x, xr.y, xr.z, xr.w};
#pragma unroll
            for (int r = 0; r < 4; ++r) {
                float v = acc[rb][cb][r] + bias + xa[r];
                size_t off = (((size_t)(pixb + r)) << 6) + co;
                ushort hh = f2bf(v);
                zh[off] = hh;
                zl[off] = f2bf(v - bf2f(hh));
            }
        }
}

// ---------------------------------------------------------------------------
// Final: BN2 apply + relu + transpose back to [B][C][H][W].
// ---------------------------------------------------------------------------
__global__ __launch_bounds__(256) void bnreluT_k(
    const float* __restrict__ c2T, const float* __restrict__ sc,
    const float* __restrict__ sh, float* __restrict__ out)
{
    __shared__ __align__(16) float T[64 * 68];
    const int b = blockIdx.x >> 6, n0 = (blockIdx.x & 63) << 6, t = threadIdx.x;
    for (int p = t; p < 1024; p += 256) {
        int n = p >> 4, c4 = (p & 15) << 2;
        float4 v = *(const float4*)&c2T[(((size_t)(b * 4096 + n0 + n)) << 6) + c4];
        float4 s4 = *(const float4*)&sc[c4];
        float4 h4 = *(const float4*)&sh[c4];
        T[(c4 + 0) * 68 + n] = fmaxf(v.x * s4.x + h4.x, 0.f);
        T[(c4 + 1) * 68 + n] = fmaxf(v.y * s4.y + h4.y, 0.f);
        T[(c4 + 2) * 68 + n] = fmaxf(v.z * s4.z + h4.z, 0.f);
        T[(c4 + 3) * 68 + n] = fmaxf(v.w * s4.w + h4.w, 0.f);
    }
    __syncthreads();
    for (int p = t; p < 1024; p += 256) {
        int c = p >> 4, n4 = (p & 15) << 2;
        float4 r;
        r.x = T[c * 68 + n4 + 0];
        r.y = T[c * 68 + n4 + 1];
        r.z = T[c * 68 + n4 + 2];
        r.w = T[c * 68 + n4 + 3];
        *(float4*)&out[(((size_t)(b * 64 + c)) << 12) + n0 + n4] = r;
    }
}

// ---------------------------------------------------------------------------
extern "C" void kernel_launch(void* const* d_in, const int* in_sizes, int n_in,
                              void* d_out, int out_size, void* d_ws,
                              size_t ws_size, hipStream_t stream)
{
    const float* x    = (const float*)d_in[0];
    const float* c1w  = (const float*)d_in[1];
    const float* bn1g = (const float*)d_in[2];
    const float* bn1b = (const float*)d_in[3];
    const float* thw  = (const float*)d_in[4];
    const float* thb  = (const float*)d_in[5];
    const float* phw  = (const float*)d_in[6];
    const float* phb  = (const float*)d_in[7];
    const float* gw   = (const float*)d_in[8];
    const float* gb   = (const float*)d_in[9];
    const float* Wwt  = (const float*)d_in[10];
    const float* Wbs  = (const float*)d_in[11];
    const float* c2w  = (const float*)d_in[12];
    const float* bn2g = (const float*)d_in[13];
    const float* bn2b = (const float*)d_in[14];
    float* out = (float*)d_out;

    float* ws = (float*)d_ws;
    // region A: xT -> x1T -> zT (bf16 hi/lo, 1M ushorts each)
    ushort* xT_hi = (ushort*)ws;
    ushort* xT_lo = xT_hi + (1 << 20);
    ushort* x1T_hi = xT_hi;  // xT dead after conv1
    ushort* x1T_lo = xT_lo;
    ushort* zT_hi = xT_hi;   // x1T dead after fused conv
    ushort* zT_lo = xT_lo;
    // region B: c1T fp32 -> yT hi/lo
    float* c1T = ws + (1 << 20);
    ushort* yT_hi = (ushort*)c1T;
    ushort* yT_lo = yT_hi + (1 << 20);
    // regions C/D/E
    ushort* thT_hi = (ushort*)(ws + (2 << 20));
    ushort* thT_lo = thT_hi + (1 << 20);
    ushort* phT_hi = (ushort*)(ws + (3 << 20));
    ushort* phT_lo = phT_hi + (1 << 20);
    ushort* g16 = (ushort*)(ws + (4 << 20));
    float* c2T = ws + (2 << 20);  // thT dead after attn
    // weights / partials / stats
    ushort* wp = (ushort*)(ws + (9 << 19));  // 4.5M floats
    float* part = ws + (5 << 20) - 33024;
    float* stats = ws + (5 << 20);
    float* sc1 = stats, *sh1 = stats + 64, *sc2 = stats + 128, *sh2 = stats + 192;

    ushort* wc1h = wp;                ushort* wc1l = wc1h + 36864;
    ushort* wthh = wp + 1 * 73728;    ushort* wthl = wthh + 36864;
    ushort* wphh = wp + 2 * 73728;    ushort* wphl = wphh + 36864;
    ushort* wgh  = wp + 3 * 73728;    ushort* wgl  = wgh + 36864;
    ushort* wc2h = wp + 4 * 73728;    ushort* wc2l = wc2h + 36864;
    ushort* w11h = wp + 5 * 73728;    ushort* w11l = w11h + 4096;

    wprep_k<<<dim3(144, 6), 256, 0, stream>>>(c1w, thw, phw, gw, c2w, Wwt, wp);
    prep0_k<<<256, 256, 0, stream>>>(x, xT_hi, xT_lo);
    conv_mfma_k<1, 0><<<256, 256, 0, stream>>>(
        xT_hi, xT_lo, wc1h, wc1l, nullptr, nullptr, nullptr, nullptr,
        nullptr, nullptr, nullptr, c1T, nullptr, nullptr, nullptr, nullptr,
        nullptr);
    bnstatA_k<<<256, 256, 0, stream>>>(c1T, part);
    bnstatB_k<<<1, 64, 0, stream>>>(part, bn1g, bn1b, sc1, sh1);
    x1prep_k<<<1024, 256, 0, stream>>>(c1T, sc1, sh1, x1T_hi, x1T_lo);
    conv_mfma_k<3, 1><<<256, 256, 0, stream>>>(
        x1T_hi, x1T_lo, wthh, wthl, wphh, wphl, wgh, wgl, thb, phb, gb,
        nullptr, thT_hi, thT_lo, phT_hi, phT_lo, g16);
    attn_k<<<256, 256, 0, stream>>>(thT_hi, thT_lo, phT_hi, phT_lo, g16,
                                    yT_hi, yT_lo);
    conv1x1_k<<<256, 256, 0, stream>>>(yT_hi, yT_lo, w11h, w11l, Wbs, x,
                                       zT_hi, zT_lo);
    conv_mfma_k<1, 0><<<256, 256, 0, stream>>>(
        zT_hi, zT_lo, wc2h, wc2l, nullptr, nullptr, nullptr, nullptr,
        nullptr, nullptr, nullptr, c2T, nullptr, nullptr, nullptr, nullptr,
        nullptr);
    bnstatA_k<<<256, 256, 0, stream>>>(c2T, part);
    bnstatB_k<<<1, 64, 0, stream>>>(part, bn2g, bn2b, sc2, sh2);
    bnreluT_k<<<256, 256, 0, stream>>>(c2T, sc2, sh2, out);
}